// Round 12
// baseline (169.127 us; speedup 1.0000x reference)
//
#include <hip/hip_runtime.h>
#include <hip/hip_bf16.h>
#include <cstdint>

// ExemplarAttention: logits[b,c] = gamma * log( sum_{n: label[n]=c} exp(-beta * d[b,n]) + eps )
// d[b,n] = x2w[b] + e2w[n] - 2 * sum_k (x[b,k]*w[k]) * E[n,k]
//
// Round 12: r10 base (best: 37.8us; r11's 2-chunk E-write was 16-way bank-conflicted,
// reverted) + 2-deep prefetch pipeline: two NAMED register sets (A/B, rule #20),
// K-loop unrolled x2; ISSUE(kt+2) at iteration top, CVTSTORE(kt+1) after MFMA.
// Global-load latency (~600-900cyc) now spans ~2 iterations instead of sitting
// inside one barrier interval (r10 PMC: MfmaUtil 15%/VALU 30%/HBM 8% = latency-bound).

typedef __attribute__((ext_vector_type(4))) float f32x4;
typedef __attribute__((ext_vector_type(8))) __bf16 bf16x8;
typedef __attribute__((ext_vector_type(4))) _Float16 half4;
typedef __attribute__((ext_vector_type(4))) unsigned int u32x4;

#define DDIM 512
#define NC 10
#define NCP 16
#define NECH 64    // exemplar chunks (16384/256)
#define EPSF 1e-9f

__device__ inline float softplus(float x) {
  return (x > 20.0f) ? x : log1pf(__expf(x));
}

// pack 2 f32 -> 2 bf16 (RNE), lo -> bits[15:0]
__device__ inline unsigned cvtpk(float lo, float hi) {
  unsigned r;
  asm("v_cvt_pk_bf16_f32 %0, %1, %2" : "=v"(r) : "v"(lo), "v"(hi));
  return r;
}

// ---- kernel 1: fused everything-but-final-reduce ----------------------------
// grid: 256 blocks (64 e-tiles x 4 b-tiles), 1024 threads = 16 waves (4E x 4B),
// wave tile 64x64. Tile 256E x 256B, BK=32, dbuf LDS 2 x (E 16KB | X 16KB) = 64KB.
// LDS chunk q (16B): row = q>>2, c = q&3, global kchunk = c ^ ((row>>1)&3).
// Staging thread t = q writes LDS-linear (16B/thread, conflict-free) from the
// pre-swizzled global chunk; readers: byte = row*64 + ((ch ^ ((row>>1)&3))*16).
__global__ __launch_bounds__(1024, 4) void gemm_mega(
    const float* __restrict__ x, const float* __restrict__ ex,
    const int* __restrict__ labels, const float* __restrict__ wu,
    const float* __restrict__ bu, float* __restrict__ part) {
  __shared__ __attribute__((aligned(16))) unsigned short smem[2 * 16384];  // 64KB dbuf
  __shared__ float wlds[512];
  __shared__ float sm[16];
  __shared__ float e2l[256];
  __shared__ float x2l[256];
  __shared__ int lab[256];
  const int tid = threadIdx.x, lane = tid & 63, wid = tid >> 6;

  // XCD-aware bijective swizzle: XCD x owns e-tiles [x*8, x*8+8) x 4 b-tiles.
  const int orig = blockIdx.x;             // 0..255
  const int xcd = orig & 7;
  const int local = orig >> 3;             // 0..31
  const int be = xcd * 8 + (local >> 2);   // exemplar tile 0..63
  const int bb = local & 3;                // batch tile 0..3

  if (tid < 256) lab[tid] = labels[be * 256 + tid];

  // ---- in-block softmax(w) + eps -> wlds (threads 0..511) ----
  if (tid < 512) {
    float v = wu[tid];
    float m = v;
    #pragma unroll
    for (int o = 32; o > 0; o >>= 1) m = fmaxf(m, __shfl_xor(m, o, 64));
    if (lane == 0) sm[wid] = m;
    __syncthreads();
    float mm = sm[0];
    #pragma unroll
    for (int i = 1; i < 8; ++i) mm = fmaxf(mm, sm[i]);
    float e = __expf(v - mm);
    float s = e;
    #pragma unroll
    for (int o = 32; o > 0; o >>= 1) s += __shfl_xor(s, o, 64);
    if (lane == 0) sm[8 + wid] = s;
    __syncthreads();
    float ss = 0.f;
    #pragma unroll
    for (int i = 0; i < 8; ++i) ss += sm[8 + i];
    wlds[tid] = e / ss + EPSF;
  } else {
    __syncthreads();
    __syncthreads();
  }
  __syncthreads();

  // ---- staging geometry (reg-staged, pre-swizzled source) ----
  const int srow = tid >> 2;                       // 0..255
  const int kc = (tid & 3) ^ ((srow >> 1) & 3);    // fixed k-chunk 0..3 (8 f32 each)
  const float* eP = ex + (size_t)(be * 256 + srow) * DDIM + kc * 8;
  const float* xP = x + (size_t)(bb * 256 + srow) * DDIM + kc * 8;
  const int dE = tid * 8;            // shorts (16B/thread, linear, conflict-free)
  const int dX = 8192 + tid * 8;

  float e2a = 0.f, x2a = 0.f;

  // ---- fragment read byte-offsets (BK=32, swizzle-matched) ----
  const int WE = (wid >> 2) * 64;    // exemplar base (0,64,128,192)
  const int WB = (wid & 3) * 64;     // batch base (0,64,128,192)
  int eoff[4], xoff[4];
  {
    const int ch = lane >> 4;        // 0..3
    #pragma unroll
    for (int f = 0; f < 4; ++f) {
      int er = WE + f * 16 + (lane & 15);
      eoff[f] = er * 64 + ((ch ^ ((er >> 1) & 3)) * 16);
      int xr = WB + f * 16 + (lane & 15);
      xoff[f] = 16384 + xr * 64 + ((ch ^ ((xr >> 1) & 3)) * 16);
    }
  }

  // two named prefetch register sets (rule #20: static names, no runtime index)
  float4 AEa, AEb, AXa, AXb;   // set A
  float4 BEa, BEb, BXa, BXb;   // set B

#define ISSUE(SET_Ea, SET_Eb, SET_Xa, SET_Xb, KT) do {                  \
    const float* p0 = eP + (KT) * 32;                                   \
    const float* p1 = xP + (KT) * 32;                                   \
    SET_Ea = *(const float4*)p0; SET_Eb = *(const float4*)(p0 + 4);     \
    SET_Xa = *(const float4*)p1; SET_Xb = *(const float4*)(p1 + 4);     \
  } while (0)

#define CVTSTORE(SET_Ea, SET_Eb, SET_Xa, SET_Xb, KT, BUFS) do {         \
    const float4 w0 = *(const float4*)&wlds[(KT) * 32 + kc * 8];        \
    const float4 w1 = *(const float4*)&wlds[(KT) * 32 + kc * 8 + 4];    \
    u32x4 pk;                                                           \
    pk[0] = cvtpk(SET_Ea.x, SET_Ea.y); pk[1] = cvtpk(SET_Ea.z, SET_Ea.w); \
    pk[2] = cvtpk(SET_Eb.x, SET_Eb.y); pk[3] = cvtpk(SET_Eb.z, SET_Eb.w); \
    e2a += SET_Ea.x*SET_Ea.x*w0.x + SET_Ea.y*SET_Ea.y*w0.y              \
         + SET_Ea.z*SET_Ea.z*w0.z + SET_Ea.w*SET_Ea.w*w0.w              \
         + SET_Eb.x*SET_Eb.x*w1.x + SET_Eb.y*SET_Eb.y*w1.y              \
         + SET_Eb.z*SET_Eb.z*w1.z + SET_Eb.w*SET_Eb.w*w1.w;             \
    *(u32x4*)&smem[(BUFS) + dE] = pk;                                   \
    float a0 = SET_Xa.x*w0.x, a1 = SET_Xa.y*w0.y, a2 = SET_Xa.z*w0.z,   \
          a3 = SET_Xa.w*w0.w, a4 = SET_Xb.x*w1.x, a5 = SET_Xb.y*w1.y,   \
          a6 = SET_Xb.z*w1.z, a7 = SET_Xb.w*w1.w;                       \
    pk[0] = cvtpk(a0, a1); pk[1] = cvtpk(a2, a3);                       \
    pk[2] = cvtpk(a4, a5); pk[3] = cvtpk(a6, a7);                       \
    x2a += a0*SET_Xa.x + a1*SET_Xa.y + a2*SET_Xa.z + a3*SET_Xa.w        \
         + a4*SET_Xb.x + a5*SET_Xb.y + a6*SET_Xb.z + a7*SET_Xb.w;       \
    *(u32x4*)&smem[(BUFS) + dX] = pk;                                   \
  } while (0)

#define MFMA_PHASE(BASEB) do {                                          \
    const char* base = (const char*)smem + (BASEB);                     \
    bf16x8 ef[4], xf[4];                                                \
    _Pragma("unroll")                                                   \
    for (int f = 0; f < 4; ++f) {                                       \
      ef[f] = *(const bf16x8*)(base + eoff[f]);                         \
      xf[f] = *(const bf16x8*)(base + xoff[f]);                         \
    }                                                                   \
    _Pragma("unroll")                                                   \
    for (int fe = 0; fe < 4; ++fe)                                      \
      _Pragma("unroll")                                                 \
      for (int fb = 0; fb < 4; ++fb)                                    \
        acc[fe][fb] = __builtin_amdgcn_mfma_f32_16x16x32_bf16(          \
            ef[fe], xf[fb], acc[fe][fb], 0, 0, 0);                      \
  } while (0)

  // prologue: A->tile0, B->tile1 in flight; stage tile0 into buffer 0
  ISSUE(AEa, AEb, AXa, AXb, 0);
  ISSUE(BEa, BEb, BXa, BXb, 1);
  CVTSTORE(AEa, AEb, AXa, AXb, 0, 0);
  __syncthreads();

  f32x4 acc[4][4] = {};
  for (int kt = 0; kt < 16; kt += 2) {
    // ---- even iteration: compute buffer 0 ----
    if (kt + 2 < 16) ISSUE(AEa, AEb, AXa, AXb, kt + 2);   // A regs free (stored at kt)
    MFMA_PHASE(0);
    CVTSTORE(BEa, BEb, BXa, BXb, kt + 1, 16384);          // B loaded ~2 iters ago
    __syncthreads();
    // ---- odd iteration: compute buffer 1 ----
    if (kt + 3 < 16) ISSUE(BEa, BEb, BXa, BXb, kt + 3);
    MFMA_PHASE(32768);
    if (kt + 2 < 16) CVTSTORE(AEa, AEb, AXa, AXb, kt + 2, 0);
    __syncthreads();
  }
#undef ISSUE
#undef CVTSTORE
#undef MFMA_PHASE

  // ---- finalize e2w / x2w: sum the 4 kc-threads of each row ----
  e2a += __shfl_xor(e2a, 1, 64); e2a += __shfl_xor(e2a, 2, 64);
  x2a += __shfl_xor(x2a, 1, 64); x2a += __shfl_xor(x2a, 2, 64);
  if ((tid & 3) == 0) {
    e2l[srow] = e2a;
    x2l[srow] = x2a;
  }
  __syncthreads();

  // ---- epilogue: sim = exp(-beta*d); class-reduce via one-hot MFMA ----
  const float beta = softplus(bu[0]) + EPSF;
  const int rb = (lane >> 4) * 4;
  const int col = lane & 15;
  float e2v[4][4];
  #pragma unroll
  for (int fe = 0; fe < 4; ++fe)
    #pragma unroll
    for (int r = 0; r < 4; ++r)
      e2v[fe][r] = e2l[WE + fe * 16 + rb + r];
  half4 oh[4];
  #pragma unroll
  for (int fe = 0; fe < 4; ++fe)
    #pragma unroll
    for (int i = 0; i < 4; ++i)
      oh[fe][i] = (lab[WE + fe * 16 + rb + i] == col) ? (_Float16)1.0f : (_Float16)0.0f;

  f32x4 csv[4];
  #pragma unroll
  for (int fb = 0; fb < 4; ++fb) {
    const float xv = x2l[WB + fb * 16 + col];
    f32x4 cs = {0.f, 0.f, 0.f, 0.f};
    #pragma unroll
    for (int fe = 0; fe < 4; ++fe) {
      half4 sa;
      #pragma unroll
      for (int r = 0; r < 4; ++r)
        sa[r] = (_Float16)__expf(-beta * (xv + e2v[fe][r] - 2.0f * acc[fe][fb][r]));
      cs = __builtin_amdgcn_mfma_f32_16x16x16f16(sa, oh[fe], cs, 0, 0, 0);
    }
    csv[fb] = cs;   // cs[r]: class-sum for batch row (WB+fb*16+rb+r), class=col
  }

  // intra-block combine of the 4 exemplar quarters via LDS (reuse smem, 64KB):
  // red[quad][brow_local 256][16], quad = WE>>6.
  float* red = (float*)smem;
  const int quad = WE >> 6;
  #pragma unroll
  for (int fb = 0; fb < 4; ++fb)
    #pragma unroll
    for (int r = 0; r < 4; ++r)
      red[((quad * 256 + (WB + fb * 16 + rb + r)) << 4) | col] = csv[fb][r];
  __syncthreads();

  // sum quarters, store block partial (256 x 16 f32) coalesced (float4/thread)
  {
    const int o = tid * 4;        // 0..4095
    const int rl = o >> 4;        // brow_local 0..255
    const int c0 = o & 12;        // 0,4,8,12
    float4 v0 = *(const float4*)&red[(rl << 4) | c0];
    float4 v1 = *(const float4*)&red[((256 + rl) << 4) | c0];
    float4 v2 = *(const float4*)&red[((512 + rl) << 4) | c0];
    float4 v3 = *(const float4*)&red[((768 + rl) << 4) | c0];
    float4 r0 = {v0.x + v1.x + v2.x + v3.x, v0.y + v1.y + v2.y + v3.y,
                 v0.z + v1.z + v2.z + v3.z, v0.w + v1.w + v2.w + v3.w};
    *(float4*)&part[(((size_t)(bb * 256 + rl)) * NECH + be) * NCP + c0] = r0;
  }
}

// ---- kernel 2: logits = gamma * log( sum_ne part[b][ne][c] + eps ) ----------
__global__ __launch_bounds__(256) void reduce_logits(
    const float* __restrict__ part, const float* __restrict__ gu,
    float* __restrict__ out) {
  const int lane = threadIdx.x & 63, wd = threadIdx.x >> 6;
  const int b = blockIdx.x * 4 + wd;
  const int cl = lane & 15, ch0 = lane >> 4;
  const float* p = part + (size_t)b * NECH * NCP;
  float v = 0.f;
  #pragma unroll
  for (int k = 0; k < 16; ++k)
    v += p[(ch0 + 4 * k) * NCP + cl];
  v += __shfl_xor(v, 16, 64);
  v += __shfl_xor(v, 32, 64);
  if (lane < NC) {
    const float gamma = softplus(gu[0]) + EPSF;
    out[b * NC + lane] = gamma * logf(v + EPSF);
  }
}

extern "C" void kernel_launch(void* const* d_in, const int* in_sizes, int n_in,
                              void* d_out, int out_size, void* d_ws, size_t ws_size,
                              hipStream_t stream) {
  const float* x  = (const float*)d_in[0];
  const float* ex = (const float*)d_in[1];
  const int* labels = (const int*)d_in[2];
  const float* wu = (const float*)d_in[3];
  const float* gu = (const float*)d_in[4];
  const float* bu = (const float*)d_in[5];
  float* out = (float*)d_out;
  const int B = in_sizes[0] / DDIM;   // 1024
  const int N = in_sizes[2];          // 16384

  float* part = (float*)d_ws;
  const size_t need = (size_t)B * NECH * NCP * 4;
  if (ws_size < need) return;   // insufficient scratch; fail loudly (zeros)

  gemm_mega<<<(N / 256) * (B / 256), 1024, 0, stream>>>(x, ex, labels, wu, bu, part);
  reduce_logits<<<B / 4, 256, 0, stream>>>(part, gu, out);
}

// Round 13
// 49.594 us; speedup vs baseline: 3.4102x; 3.4102x over previous
//
#include <hip/hip_runtime.h>
#include <hip/hip_bf16.h>
#include <cstdint>

// ExemplarAttention: logits[b,c] = gamma * log( sum_{n: label[n]=c} exp(-beta * d[b,n]) + eps )
// d[b,n] = x2w[b] + e2w[n] - 2 * sum_k (x[b,k]*w[k]) * E[n,k]
//
// Round 13: r10 base (best 37.8us). r12 spilled (128-reg cap was already saturated:
// 64 VGPR + 64 AGPR acc). Pay for pipeline depth by removing X from the register path:
//  - prep_x kernel: softmax(w)->wbuf, bf16(x*w)->xbf, x2w. ~3MB, ~2us.
//  - gemm: X staged via global_load_lds DMA (pre-swizzled source, linear dest, 0 VGPR,
//    0 VALU); E keeps r10's 1-chunk/thread staging (conflict-free) but with DEPTH-2
//    prefetch (two named reg sets, x2-unrolled loop) - net VGPR delta ~0 vs r10.
//  - kills the 64x-redundant in-gemm X cvt (half of r10's staging VALU).
// Same validated (row>>1)&3 both-sides swizzle, one-hot-MFMA class reduce, no atomics.

typedef __attribute__((ext_vector_type(4))) float f32x4;
typedef __attribute__((ext_vector_type(8))) __bf16 bf16x8;
typedef __attribute__((ext_vector_type(4))) _Float16 half4;
typedef __attribute__((ext_vector_type(4))) unsigned int u32x4;

#define DDIM 512
#define NC 10
#define NCP 16
#define NECH 64    // exemplar chunks (16384/256)
#define EPSF 1e-9f

typedef const __attribute__((address_space(1))) void* gas_ptr;
typedef __attribute__((address_space(3))) void* las_ptr;

__device__ inline void async16(const void* g, void* l) {
  __builtin_amdgcn_global_load_lds((gas_ptr)g, (las_ptr)l, 16, 0, 0);
}

__device__ inline float softplus(float x) {
  return (x > 20.0f) ? x : log1pf(__expf(x));
}

// pack 2 f32 -> 2 bf16 (RNE), lo -> bits[15:0]
__device__ inline unsigned cvtpk(float lo, float hi) {
  unsigned r;
  asm("v_cvt_pk_bf16_f32 %0, %1, %2" : "=v"(r) : "v"(lo), "v"(hi));
  return r;
}

// ---- kernel 1: softmax(w) -> wbuf; X -> bf16(x*w) + x2w ---------------------
// 128 blocks x 512 threads; one row per wave (8 rows/block).
__global__ __launch_bounds__(512) void prep_x(
    const float* __restrict__ x, const float* __restrict__ wu,
    float* __restrict__ wbuf, unsigned short* __restrict__ xbf,
    float* __restrict__ x2w) {
  __shared__ float sm[16];
  __shared__ float wlds[512];
  const int tid = threadIdx.x, lane = tid & 63, wid = tid >> 6;

  float v = wu[tid];
  float m = v;
  #pragma unroll
  for (int o = 32; o > 0; o >>= 1) m = fmaxf(m, __shfl_xor(m, o, 64));
  if (lane == 0) sm[wid] = m;
  __syncthreads();
  float mm = sm[0];
  #pragma unroll
  for (int i = 1; i < 8; ++i) mm = fmaxf(mm, sm[i]);
  float e = __expf(v - mm);
  float s = e;
  #pragma unroll
  for (int o = 32; o > 0; o >>= 1) s += __shfl_xor(s, o, 64);
  if (lane == 0) sm[8 + wid] = s;
  __syncthreads();
  float ss = 0.f;
  #pragma unroll
  for (int i = 0; i < 8; ++i) ss += sm[8 + i];
  const float wv = e / ss + EPSF;
  wbuf[tid] = wv;     // all blocks write identical values (deterministic)
  wlds[tid] = wv;
  __syncthreads();
  const float4 wa = *(const float4*)&wlds[lane * 8];
  const float4 wb = *(const float4*)&wlds[lane * 8 + 4];

  const size_t row = (size_t)blockIdx.x * 8 + wid;
  const float* p = x + row * DDIM + lane * 8;
  float4 va = *(const float4*)(p);
  float4 vb = *(const float4*)(p + 4);
  float a0 = va.x * wa.x, a1 = va.y * wa.y, a2 = va.z * wa.z, a3 = va.w * wa.w;
  float a4 = vb.x * wb.x, a5 = vb.y * wb.y, a6 = vb.z * wb.z, a7 = vb.w * wb.w;
  float s2 = a0 * va.x + a1 * va.y + a2 * va.z + a3 * va.w
           + a4 * vb.x + a5 * vb.y + a6 * vb.z + a7 * vb.w;
  u32x4 pk;
  pk[0] = cvtpk(a0, a1); pk[1] = cvtpk(a2, a3);
  pk[2] = cvtpk(a4, a5); pk[3] = cvtpk(a6, a7);
  *(u32x4*)(xbf + row * DDIM + lane * 8) = pk;
  #pragma unroll
  for (int o = 32; o > 0; o >>= 1) s2 += __shfl_xor(s2, o, 64);
  if (lane == 0) x2w[row] = s2;
}

// ---- kernel 2: fused GEMM + exp + class partial reduce ----------------------
// grid: 256 blocks (64 e-tiles x 4 b-tiles), 1024 threads = 16 waves (4E x 4B),
// wave tile 64x64. Tile 256E x 256B, BK=32, dbuf LDS 2 x (E 16KB | X 16KB) = 64KB.
// LDS chunk q (16B): row = q>>2, c = q&3, global kchunk = c ^ ((row>>1)&3).
// E: reg-staged (1 chunk/thread, 16B linear write); X: global_load_lds DMA from xbf
// (pre-swizzled source, linear dest). Readers: byte = row*64 + ((ch^((row>>1)&3))*16).
__global__ __launch_bounds__(1024, 4) void gemm_mega(
    const float* __restrict__ ex, const unsigned short* __restrict__ xbf,
    const int* __restrict__ labels, const float* __restrict__ wbuf,
    const float* __restrict__ x2w, const float* __restrict__ bu,
    float* __restrict__ part) {
  __shared__ __attribute__((aligned(16))) unsigned short smem[2 * 16384];  // 64KB dbuf
  __shared__ float wlds[512];
  __shared__ float e2l[256];
  __shared__ int lab[256];
  const int tid = threadIdx.x, lane = tid & 63, wid = tid >> 6;

  // XCD-aware bijective swizzle: XCD x owns e-tiles [x*8, x*8+8) x 4 b-tiles.
  const int orig = blockIdx.x;             // 0..255
  const int xcd = orig & 7;
  const int local = orig >> 3;             // 0..31
  const int be = xcd * 8 + (local >> 2);   // exemplar tile 0..63
  const int bb = local & 3;                // batch tile 0..3

  if (tid < 256) lab[tid] = labels[be * 256 + tid];
  if (tid < 512) wlds[tid] = wbuf[tid];

  // ---- staging geometry (pre-swizzled sources) ----
  const int srow = tid >> 2;                       // 0..255
  const int kc = (tid & 3) ^ ((srow >> 1) & 3);    // fixed k-chunk 0..3
  const float* eP = ex + (size_t)(be * 256 + srow) * DDIM + kc * 8;
  const unsigned short* xP = xbf + (size_t)(bb * 256 + srow) * DDIM + kc * 8;
  const int dE = tid * 8;            // shorts (16B/thread, linear, conflict-free)
  const int dX = 8192 + tid * 8;

  float e2a = 0.f;

  // ---- fragment read byte-offsets (BK=32, swizzle-matched) ----
  const int WE = (wid >> 2) * 64;    // exemplar base (0,64,128,192)
  const int WB = (wid & 3) * 64;     // batch base (0,64,128,192)
  int eoff[4], xoff[4];
  {
    const int ch = lane >> 4;        // 0..3
    #pragma unroll
    for (int f = 0; f < 4; ++f) {
      int er = WE + f * 16 + (lane & 15);
      eoff[f] = er * 64 + ((ch ^ ((er >> 1) & 3)) * 16);
      int xr = WB + f * 16 + (lane & 15);
      xoff[f] = 16384 + xr * 64 + ((ch ^ ((xr >> 1) & 3)) * 16);
    }
  }

  // two named E prefetch sets (rule #20: static names, no runtime index)
  float4 AEa, AEb, BEa, BEb;

#define ISSUE_E(Ea, Eb, KT) do {                                        \
    const float* p0 = eP + (KT) * 32;                                   \
    Ea = *(const float4*)p0; Eb = *(const float4*)(p0 + 4);             \
  } while (0)

#define CVTSTORE_E(Ea, Eb, KT, BUFS) do {                               \
    const float4 w0 = *(const float4*)&wlds[(KT) * 32 + kc * 8];        \
    const float4 w1 = *(const float4*)&wlds[(KT) * 32 + kc * 8 + 4];    \
    u32x4 pk;                                                           \
    pk[0] = cvtpk(Ea.x, Ea.y); pk[1] = cvtpk(Ea.z, Ea.w);               \
    pk[2] = cvtpk(Eb.x, Eb.y); pk[3] = cvtpk(Eb.z, Eb.w);               \
    e2a += Ea.x*Ea.x*w0.x + Ea.y*Ea.y*w0.y                              \
         + Ea.z*Ea.z*w0.z + Ea.w*Ea.w*w0.w                              \
         + Eb.x*Eb.x*w1.x + Eb.y*Eb.y*w1.y                              \
         + Eb.z*Eb.z*w1.z + Eb.w*Eb.w*w1.w;                             \
    *(u32x4*)&smem[(BUFS) + dE] = pk;                                   \
  } while (0)

#define MFMA_PHASE(BASEB) do {                                          \
    const char* base = (const char*)smem + (BASEB);                     \
    bf16x8 ef[4], xf[4];                                                \
    _Pragma("unroll")                                                   \
    for (int f = 0; f < 4; ++f) {                                       \
      ef[f] = *(const bf16x8*)(base + eoff[f]);                         \
      xf[f] = *(const bf16x8*)(base + xoff[f]);                         \
    }                                                                   \
    _Pragma("unroll")                                                   \
    for (int fe = 0; fe < 4; ++fe)                                      \
      _Pragma("unroll")                                                 \
      for (int fb = 0; fb < 4; ++fb)                                    \
        acc[fe][fb] = __builtin_amdgcn_mfma_f32_16x16x32_bf16(          \
            ef[fe], xf[fb], acc[fe][fb], 0, 0, 0);                      \
  } while (0)

  // prologue: E(0),E(1) in registers; X(0) DMA -> buf0; stage E(0) -> buf0
  ISSUE_E(AEa, AEb, 0);
  ISSUE_E(BEa, BEb, 1);
  async16(xP, &smem[dX]);
  __syncthreads();                  // wlds visible (also drains X(0) early)
  CVTSTORE_E(AEa, AEb, 0, 0);
  __syncthreads();                  // buf0 E written; X(0) landed

  f32x4 acc[4][4] = {};
  for (int kt = 0; kt < 16; kt += 2) {
    // ---- even: compute buf0 (tile kt) ----
    async16(xP + (kt + 1) * 32, &smem[16384 + dX]);   // X(kt+1) -> buf1
    if (kt + 2 < 16) ISSUE_E(AEa, AEb, kt + 2);       // A regs free (stored at kt)
    MFMA_PHASE(0);
    CVTSTORE_E(BEa, BEb, kt + 1, 16384);              // E(kt+1) -> buf1
    __syncthreads();
    // ---- odd: compute buf1 (tile kt+1) ----
    if (kt + 2 < 16) {
      async16(xP + (kt + 2) * 32, &smem[dX]);         // X(kt+2) -> buf0
      ISSUE_E(BEa, BEb, kt + 3 < 16 ? kt + 3 : kt + 2);  // prefetch (dummy-safe)
    }
    MFMA_PHASE(32768);
    if (kt + 2 < 16) CVTSTORE_E(AEa, AEb, kt + 2, 0); // E(kt+2) -> buf0
    __syncthreads();
  }
#undef ISSUE_E
#undef CVTSTORE_E
#undef MFMA_PHASE

  // ---- finalize e2w: sum the 4 kc-threads of each row ----
  e2a += __shfl_xor(e2a, 1, 64); e2a += __shfl_xor(e2a, 2, 64);
  if ((tid & 3) == 0) e2l[srow] = e2a;
  __syncthreads();

  // ---- epilogue: sim = exp(-beta*d); class-reduce via one-hot MFMA ----
  const float beta = softplus(bu[0]) + EPSF;
  const int rb = (lane >> 4) * 4;
  const int col = lane & 15;
  float e2v[4][4];
  #pragma unroll
  for (int fe = 0; fe < 4; ++fe)
    #pragma unroll
    for (int r = 0; r < 4; ++r)
      e2v[fe][r] = e2l[WE + fe * 16 + rb + r];
  half4 oh[4];
  #pragma unroll
  for (int fe = 0; fe < 4; ++fe)
    #pragma unroll
    for (int i = 0; i < 4; ++i)
      oh[fe][i] = (lab[WE + fe * 16 + rb + i] == col) ? (_Float16)1.0f : (_Float16)0.0f;

  f32x4 csv[4];
  #pragma unroll
  for (int fb = 0; fb < 4; ++fb) {
    const float xv = x2w[bb * 256 + WB + fb * 16 + col];
    f32x4 cs = {0.f, 0.f, 0.f, 0.f};
    #pragma unroll
    for (int fe = 0; fe < 4; ++fe) {
      half4 sa;
      #pragma unroll
      for (int r = 0; r < 4; ++r)
        sa[r] = (_Float16)__expf(-beta * (xv + e2v[fe][r] - 2.0f * acc[fe][fb][r]));
      cs = __builtin_amdgcn_mfma_f32_16x16x16f16(sa, oh[fe], cs, 0, 0, 0);
    }
    csv[fb] = cs;   // cs[r]: class-sum for batch row (WB+fb*16+rb+r), class=col
  }

  // intra-block combine of the 4 exemplar quarters via LDS (reuse smem, 64KB):
  // red[quad][brow_local 256][16], quad = WE>>6.
  float* red = (float*)smem;
  const int quad = WE >> 6;
  #pragma unroll
  for (int fb = 0; fb < 4; ++fb)
    #pragma unroll
    for (int r = 0; r < 4; ++r)
      red[((quad * 256 + (WB + fb * 16 + rb + r)) << 4) | col] = csv[fb][r];
  __syncthreads();

  // sum quarters, store block partial (256 x 16 f32) coalesced (float4/thread)
  {
    const int o = tid * 4;        // 0..4095
    const int rl = o >> 4;        // brow_local 0..255
    const int c0 = o & 12;        // 0,4,8,12
    float4 v0 = *(const float4*)&red[(rl << 4) | c0];
    float4 v1 = *(const float4*)&red[((256 + rl) << 4) | c0];
    float4 v2 = *(const float4*)&red[((512 + rl) << 4) | c0];
    float4 v3 = *(const float4*)&red[((768 + rl) << 4) | c0];
    float4 r0 = {v0.x + v1.x + v2.x + v3.x, v0.y + v1.y + v2.y + v3.y,
                 v0.z + v1.z + v2.z + v3.z, v0.w + v1.w + v2.w + v3.w};
    *(float4*)&part[(((size_t)(bb * 256 + rl)) * NECH + be) * NCP + c0] = r0;
  }
}

// ---- kernel 3: logits = gamma * log( sum_ne part[b][ne][c] + eps ) ----------
__global__ __launch_bounds__(256) void reduce_logits(
    const float* __restrict__ part, const float* __restrict__ gu,
    float* __restrict__ out) {
  const int lane = threadIdx.x & 63, wd = threadIdx.x >> 6;
  const int b = blockIdx.x * 4 + wd;
  const int cl = lane & 15, ch0 = lane >> 4;
  const float* p = part + (size_t)b * NECH * NCP;
  float v = 0.f;
  #pragma unroll
  for (int k = 0; k < 16; ++k)
    v += p[(ch0 + 4 * k) * NCP + cl];
  v += __shfl_xor(v, 16, 64);
  v += __shfl_xor(v, 32, 64);
  if (lane < NC) {
    const float gamma = softplus(gu[0]) + EPSF;
    out[b * NC + lane] = gamma * logf(v + EPSF);
  }
}

extern "C" void kernel_launch(void* const* d_in, const int* in_sizes, int n_in,
                              void* d_out, int out_size, void* d_ws, size_t ws_size,
                              hipStream_t stream) {
  const float* x  = (const float*)d_in[0];
  const float* ex = (const float*)d_in[1];
  const int* labels = (const int*)d_in[2];
  const float* wu = (const float*)d_in[3];
  const float* gu = (const float*)d_in[4];
  const float* bu = (const float*)d_in[5];
  float* out = (float*)d_out;
  const int B = in_sizes[0] / DDIM;   // 1024
  const int N = in_sizes[2];          // 16384

  char* ws = (char*)d_ws;
  const size_t off_w    = 0;
  const size_t off_x2w  = 4096;
  const size_t off_xbf  = off_x2w + (size_t)B * 4;
  const size_t off_part = off_xbf + (size_t)B * DDIM * 2;
  const size_t need     = off_part + (size_t)B * NECH * NCP * 4;
  if (ws_size < need) return;   // insufficient scratch; fail loudly (zeros)

  float* wbuf = (float*)(ws + off_w);
  float* x2w  = (float*)(ws + off_x2w);
  unsigned short* xbf = (unsigned short*)(ws + off_xbf);
  float* part = (float*)(ws + off_part);

  prep_x<<<B / 8, 512, 0, stream>>>(x, wu, wbuf, xbf, x2w);
  gemm_mega<<<(N / 256) * (B / 256), 1024, 0, stream>>>(ex, xbf, labels, wbuf, x2w, bu, part);
  reduce_logits<<<B / 4, 256, 0, stream>>>(part, gu, out);
}

// Round 14
// 42.246 us; speedup vs baseline: 4.0034x; 1.1739x over previous
//
#include <hip/hip_runtime.h>
#include <hip/hip_bf16.h>
#include <cstdint>

// ExemplarAttention: logits[b,c] = gamma * log( sum_{n: label[n]=c} exp(-beta * d[b,n]) + eps )
// d[b,n] = x2w[b] + e2w[n] - 2 * sum_k (x[b,k]*w[k]) * E[n,k]
//
// Round 14: r11's geometry with its one bug fixed. r11 regressed ONLY because E's
// 2-chunk/thread ds_write used a 32B/lane stride (16-way bank conflict, 1.18M).
// Fix: two separate LINEAR stores (chunk t -> tid*8, chunk 512+t -> (512+tid)*8;
// each 16B/lane consecutive = conflict-free). Depth-1 pipeline only (r12/r13 proved
// any named depth-2 prefetch spills at this register budget).
//  - prep_x: softmax(w)->wbuf, bf16(x*w)->xbf, x2w  (~3MB, ~2us)
//  - gemm: 512 blocks x 512 thr (8 waves, 4Ex2B), tile 256Ex128B, BK=32, 48KB dbuf
//    -> 2 independent blocks/CU (cross-block barrier-drain hiding). X via
//    global_load_lds DMA (pre-swizzled source); E reg-staged with fused e2w.
//    Both-sides (row>>1)&3 swizzle; one-hot-MFMA class reduce; no atomics.

typedef __attribute__((ext_vector_type(4))) float f32x4;
typedef __attribute__((ext_vector_type(8))) __bf16 bf16x8;
typedef __attribute__((ext_vector_type(4))) _Float16 half4;
typedef __attribute__((ext_vector_type(4))) unsigned int u32x4;

#define DDIM 512
#define NC 10
#define NCP 16
#define NECH 64    // exemplar chunks (16384/256)
#define EPSF 1e-9f

typedef const __attribute__((address_space(1))) void* gas_ptr;
typedef __attribute__((address_space(3))) void* las_ptr;

__device__ inline void async16(const void* g, void* l) {
  __builtin_amdgcn_global_load_lds((gas_ptr)g, (las_ptr)l, 16, 0, 0);
}

__device__ inline float softplus(float x) {
  return (x > 20.0f) ? x : log1pf(__expf(x));
}

// pack 2 f32 -> 2 bf16 (RNE), lo -> bits[15:0]
__device__ inline unsigned cvtpk(float lo, float hi) {
  unsigned r;
  asm("v_cvt_pk_bf16_f32 %0, %1, %2" : "=v"(r) : "v"(lo), "v"(hi));
  return r;
}

// ---- kernel 1: softmax(w) -> wbuf; X -> bf16(x*w) + x2w ---------------------
// 128 blocks x 512 threads; one row per wave (8 rows/block).
__global__ __launch_bounds__(512) void prep_x(
    const float* __restrict__ x, const float* __restrict__ wu,
    float* __restrict__ wbuf, unsigned short* __restrict__ xbf,
    float* __restrict__ x2w) {
  __shared__ float sm[16];
  __shared__ float wlds[512];
  const int tid = threadIdx.x, lane = tid & 63, wid = tid >> 6;

  float v = wu[tid];
  float m = v;
  #pragma unroll
  for (int o = 32; o > 0; o >>= 1) m = fmaxf(m, __shfl_xor(m, o, 64));
  if (lane == 0) sm[wid] = m;
  __syncthreads();
  float mm = sm[0];
  #pragma unroll
  for (int i = 1; i < 8; ++i) mm = fmaxf(mm, sm[i]);
  float e = __expf(v - mm);
  float s = e;
  #pragma unroll
  for (int o = 32; o > 0; o >>= 1) s += __shfl_xor(s, o, 64);
  if (lane == 0) sm[8 + wid] = s;
  __syncthreads();
  float ss = 0.f;
  #pragma unroll
  for (int i = 0; i < 8; ++i) ss += sm[8 + i];
  const float wv = e / ss + EPSF;
  wbuf[tid] = wv;     // all blocks write identical values (deterministic)
  wlds[tid] = wv;
  __syncthreads();
  const float4 wa = *(const float4*)&wlds[lane * 8];
  const float4 wb = *(const float4*)&wlds[lane * 8 + 4];

  const size_t row = (size_t)blockIdx.x * 8 + wid;
  const float* p = x + row * DDIM + lane * 8;
  float4 va = *(const float4*)(p);
  float4 vb = *(const float4*)(p + 4);
  float a0 = va.x * wa.x, a1 = va.y * wa.y, a2 = va.z * wa.z, a3 = va.w * wa.w;
  float a4 = vb.x * wb.x, a5 = vb.y * wb.y, a6 = vb.z * wb.z, a7 = vb.w * wb.w;
  float s2 = a0 * va.x + a1 * va.y + a2 * va.z + a3 * va.w
           + a4 * vb.x + a5 * vb.y + a6 * vb.z + a7 * vb.w;
  u32x4 pk;
  pk[0] = cvtpk(a0, a1); pk[1] = cvtpk(a2, a3);
  pk[2] = cvtpk(a4, a5); pk[3] = cvtpk(a6, a7);
  *(u32x4*)(xbf + row * DDIM + lane * 8) = pk;
  #pragma unroll
  for (int o = 32; o > 0; o >>= 1) s2 += __shfl_xor(s2, o, 64);
  if (lane == 0) x2w[row] = s2;
}

// ---- kernel 2: fused GEMM + exp + class partial reduce ----------------------
// grid: 512 blocks (64 e-tiles x 8 b-tiles), 512 threads = 8 waves (4E x 2B),
// wave tile 64x64. Tile 256E x 128B, BK=32, dbuf 2 x (E 16KB | X 8KB) = 48KB.
// LDS chunk i (16B): row = i>>2, pos = i&3, global kchunk = pos ^ ((row>>1)&3).
// E: thread t reg-stages chunks t (row t>>2) and 512+t (row 128+(t>>2)), two linear
// 16B/lane stores. X: global_load_lds DMA (pre-swizzled source, linear dest).
// Readers: byte = row*64 + ((ch ^ ((row>>1)&3))*16).
__global__ __launch_bounds__(512, 4) void gemm_mega(
    const float* __restrict__ ex, const unsigned short* __restrict__ xbf,
    const int* __restrict__ labels, const float* __restrict__ wbuf,
    const float* __restrict__ x2w, const float* __restrict__ bu,
    float* __restrict__ part) {
  __shared__ __attribute__((aligned(16))) unsigned short smem[2 * 12288];  // 48KB dbuf
  __shared__ float wlds[512];
  __shared__ float e2l[256];
  __shared__ int lab[256];
  const int tid = threadIdx.x, lane = tid & 63, wid = tid >> 6;

  // XCD-aware bijective swizzle: XCD x owns e-tiles [x*8, x*8+8) x 8 b-tiles.
  const int orig = blockIdx.x;             // 0..511
  const int xcd = orig & 7;
  const int local = orig >> 3;             // 0..63
  const int be = xcd * 8 + (local >> 3);   // exemplar tile 0..63
  const int bb = local & 7;                // batch tile 0..7

  if (tid < 256) lab[tid] = labels[be * 256 + tid];
  wlds[tid] = wbuf[tid];

  // ---- E staging geometry: chunks t and 512+t (rows srow, srow+128) ----
  const int srow = tid >> 2;                       // 0..127
  const int kc = (tid & 3) ^ ((srow >> 1) & 3);    // same for both rows (128%4==0 in (row>>1)&3)
  const float* eP0 = ex + (size_t)(be * 256 + srow) * DDIM + kc * 8;
  const float* eP1 = ex + (size_t)(be * 256 + 128 + srow) * DDIM + kc * 8;
  const int dE0 = tid * 8;                         // shorts, linear (conflict-free)
  const int dE1 = (512 + tid) * 8;

  // ---- X staging geometry (async DMA, pre-swizzled source) ----
  const int xrow = tid >> 2;                       // 0..127
  const int xkc = (tid & 3) ^ ((xrow >> 1) & 3);
  const unsigned short* xP = xbf + (size_t)(bb * 128 + xrow) * DDIM + xkc * 8;
  const int dX = 8192 + tid * 8;                   // shorts, X block at +8192

  float e2a0 = 0.f, e2a1 = 0.f;

  // ---- fragment read byte-offsets (BK=32, swizzle-matched) ----
  const int WE = (wid >> 1) * 64;    // exemplar base (0,64,128,192)
  const int WB = (wid & 1) * 64;     // batch base (0,64)
  int eoff[4], xoff[4];
  {
    const int ch = lane >> 4;        // 0..3
    #pragma unroll
    for (int f = 0; f < 4; ++f) {
      int er = WE + f * 16 + (lane & 15);
      eoff[f] = er * 64 + ((ch ^ ((er >> 1) & 3)) * 16);
      int xr = WB + f * 16 + (lane & 15);
      xoff[f] = 16384 + xr * 64 + ((ch ^ ((xr >> 1) & 3)) * 16);
    }
  }

  float4 sEa, sEb, sEc, sEd;

#define ISSUE(KT) do {                                                  \
    const float* p0 = eP0 + (KT) * 32;                                  \
    const float* p1 = eP1 + (KT) * 32;                                  \
    sEa = *(const float4*)p0; sEb = *(const float4*)(p0 + 4);           \
    sEc = *(const float4*)p1; sEd = *(const float4*)(p1 + 4);           \
  } while (0)

#define CVTSTORE(KT, BUFS) do {                                         \
    const float4 w0 = *(const float4*)&wlds[(KT) * 32 + kc * 8];        \
    const float4 w1 = *(const float4*)&wlds[(KT) * 32 + kc * 8 + 4];    \
    u32x4 pk;                                                           \
    pk[0] = cvtpk(sEa.x, sEa.y); pk[1] = cvtpk(sEa.z, sEa.w);           \
    pk[2] = cvtpk(sEb.x, sEb.y); pk[3] = cvtpk(sEb.z, sEb.w);           \
    e2a0 += sEa.x*sEa.x*w0.x + sEa.y*sEa.y*w0.y                         \
          + sEa.z*sEa.z*w0.z + sEa.w*sEa.w*w0.w                         \
          + sEb.x*sEb.x*w1.x + sEb.y*sEb.y*w1.y                         \
          + sEb.z*sEb.z*w1.z + sEb.w*sEb.w*w1.w;                        \
    *(u32x4*)&smem[(BUFS) + dE0] = pk;                                  \
    pk[0] = cvtpk(sEc.x, sEc.y); pk[1] = cvtpk(sEc.z, sEc.w);           \
    pk[2] = cvtpk(sEd.x, sEd.y); pk[3] = cvtpk(sEd.z, sEd.w);           \
    e2a1 += sEc.x*sEc.x*w0.x + sEc.y*sEc.y*w0.y                         \
          + sEc.z*sEc.z*w0.z + sEc.w*sEc.w*w0.w                         \
          + sEd.x*sEd.x*w1.x + sEd.y*sEd.y*w1.y                         \
          + sEd.z*sEd.z*w1.z + sEd.w*sEd.w*w1.w;                        \
    *(u32x4*)&smem[(BUFS) + dE1] = pk;                                  \
  } while (0)

#define MFMA_PHASE(BASEB) do {                                          \
    const char* base = (const char*)smem + (BASEB);                     \
    bf16x8 ef[4], xf[4];                                                \
    _Pragma("unroll")                                                   \
    for (int f = 0; f < 4; ++f) {                                       \
      ef[f] = *(const bf16x8*)(base + eoff[f]);                         \
      xf[f] = *(const bf16x8*)(base + xoff[f]);                         \
    }                                                                   \
    _Pragma("unroll")                                                   \
    for (int fe = 0; fe < 4; ++fe)                                      \
      _Pragma("unroll")                                                 \
      for (int fb = 0; fb < 4; ++fb)                                    \
        acc[fe][fb] = __builtin_amdgcn_mfma_f32_16x16x32_bf16(          \
            ef[fe], xf[fb], acc[fe][fb], 0, 0, 0);                      \
  } while (0)

  __syncthreads();   // wlds ready

  // prologue: stage K-tile 0 into buffer 0
  ISSUE(0);
  async16(xP, &smem[dX]);
  CVTSTORE(0, 0);
  __syncthreads();

  f32x4 acc[4][4] = {};
  for (int kt = 0; kt < 16; ++kt) {
    const int cur = kt & 1;
    const int nb = (cur ^ 1) * 12288;              // shorts
    if (kt < 15) {
      ISSUE(kt + 1);                               // E f32 loads fly under MFMA
      async16(xP + (kt + 1) * 32, &smem[nb + dX]); // X DMA into other buffer
    }
    MFMA_PHASE(cur * 24576);
    if (kt < 15) CVTSTORE(kt + 1, nb);
    __syncthreads();   // reads of cur done; next-tile E writes + X DMA landed
  }
#undef ISSUE
#undef CVTSTORE
#undef MFMA_PHASE

  // ---- finalize e2w: sum the 4 kc-threads of each row ----
  e2a0 += __shfl_xor(e2a0, 1, 64); e2a0 += __shfl_xor(e2a0, 2, 64);
  e2a1 += __shfl_xor(e2a1, 1, 64); e2a1 += __shfl_xor(e2a1, 2, 64);
  if ((tid & 3) == 0) {
    e2l[srow] = e2a0;
    e2l[128 + srow] = e2a1;
  }
  __syncthreads();

  // ---- epilogue: sim = exp(-beta*d); class-reduce via one-hot MFMA ----
  const float beta = softplus(bu[0]) + EPSF;
  const int rb = (lane >> 4) * 4;
  const int col = lane & 15;
  float e2v[4][4];
  #pragma unroll
  for (int fe = 0; fe < 4; ++fe)
    #pragma unroll
    for (int r = 0; r < 4; ++r)
      e2v[fe][r] = e2l[WE + fe * 16 + rb + r];
  half4 oh[4];
  #pragma unroll
  for (int fe = 0; fe < 4; ++fe)
    #pragma unroll
    for (int i = 0; i < 4; ++i)
      oh[fe][i] = (lab[WE + fe * 16 + rb + i] == col) ? (_Float16)1.0f : (_Float16)0.0f;

  f32x4 csv[4];
  #pragma unroll
  for (int fb = 0; fb < 4; ++fb) {
    const float xv = x2w[bb * 128 + WB + fb * 16 + col];
    f32x4 cs = {0.f, 0.f, 0.f, 0.f};
    #pragma unroll
    for (int fe = 0; fe < 4; ++fe) {
      half4 sa;
      #pragma unroll
      for (int r = 0; r < 4; ++r)
        sa[r] = (_Float16)__expf(-beta * (xv + e2v[fe][r] - 2.0f * acc[fe][fb][r]));
      cs = __builtin_amdgcn_mfma_f32_16x16x16f16(sa, oh[fe], cs, 0, 0, 0);
    }
    csv[fb] = cs;   // cs[r]: class-sum for batch row (WB+fb*16+rb+r), class=col
  }

  // intra-block combine of the 4 exemplar quarters via LDS (reuse smem, 32KB):
  // red[quad][brow_local 128][16], quad = WE>>6.
  float* red = (float*)smem;
  const int quad = WE >> 6;
  #pragma unroll
  for (int fb = 0; fb < 4; ++fb)
    #pragma unroll
    for (int r = 0; r < 4; ++r)
      red[((quad * 128 + (WB + fb * 16 + rb + r)) << 4) | col] = csv[fb][r];
  __syncthreads();

  // sum quarters, store block partial (128 x 16 f32) coalesced (float4/thread)
  {
    const int o = tid * 4;        // 0..2047
    const int rl = o >> 4;        // brow_local 0..127
    const int c0b = o & 12;       // 0,4,8,12
    float4 v0 = *(const float4*)&red[(rl << 4) | c0b];
    float4 v1 = *(const float4*)&red[((128 + rl) << 4) | c0b];
    float4 v2 = *(const float4*)&red[((256 + rl) << 4) | c0b];
    float4 v3 = *(const float4*)&red[((384 + rl) << 4) | c0b];
    float4 r0 = {v0.x + v1.x + v2.x + v3.x, v0.y + v1.y + v2.y + v3.y,
                 v0.z + v1.z + v2.z + v3.z, v0.w + v1.w + v2.w + v3.w};
    *(float4*)&part[(((size_t)(bb * 128 + rl)) * NECH + be) * NCP + c0b] = r0;
  }
}

// ---- kernel 3: logits = gamma * log( sum_ne part[b][ne][c] + eps ) ----------
__global__ __launch_bounds__(256) void reduce_logits(
    const float* __restrict__ part, const float* __restrict__ gu,
    float* __restrict__ out) {
  const int lane = threadIdx.x & 63, wd = threadIdx.x >> 6;
  const int b = blockIdx.x * 4 + wd;
  const int cl = lane & 15, ch0 = lane >> 4;
  const float* p = part + (size_t)b * NECH * NCP;
  float v = 0.f;
  #pragma unroll
  for (int k = 0; k < 16; ++k)
    v += p[(ch0 + 4 * k) * NCP + cl];
  v += __shfl_xor(v, 16, 64);
  v += __shfl_xor(v, 32, 64);
  if (lane < NC) {
    const float gamma = softplus(gu[0]) + EPSF;
    out[b * NC + lane] = gamma * logf(v + EPSF);
  }
}

extern "C" void kernel_launch(void* const* d_in, const int* in_sizes, int n_in,
                              void* d_out, int out_size, void* d_ws, size_t ws_size,
                              hipStream_t stream) {
  const float* x  = (const float*)d_in[0];
  const float* ex = (const float*)d_in[1];
  const int* labels = (const int*)d_in[2];
  const float* wu = (const float*)d_in[3];
  const float* gu = (const float*)d_in[4];
  const float* bu = (const float*)d_in[5];
  float* out = (float*)d_out;
  const int B = in_sizes[0] / DDIM;   // 1024
  const int N = in_sizes[2];          // 16384

  char* ws = (char*)d_ws;
  const size_t off_w    = 0;
  const size_t off_x2w  = 4096;
  const size_t off_xbf  = off_x2w + (size_t)B * 4;
  const size_t off_part = off_xbf + (size_t)B * DDIM * 2;
  const size_t need     = off_part + (size_t)B * NECH * NCP * 4;
  if (ws_size < need) return;   // insufficient scratch; fail loudly (zeros)

  float* wbuf = (float*)(ws + off_w);
  float* x2w  = (float*)(ws + off_x2w);
  unsigned short* xbf = (unsigned short*)(ws + off_xbf);
  float* part = (float*)(ws + off_part);

  prep_x<<<B / 8, 512, 0, stream>>>(x, wu, wbuf, xbf, x2w);
  gemm_mega<<<(N / 256) * (B / 128), 512, 0, stream>>>(ex, xbf, labels, wbuf, x2w, bu, part);
  reduce_logits<<<B / 4, 256, 0, stream>>>(part, gu, out);
}